// Round 9
// baseline (161.939 us; speedup 1.0000x reference)
//
#include <hip/hip_runtime.h>

#define BB 16
#define CC 80
#define DD 1024
#define HW 196
#define NSP (BB * HW)        // 3136 = 49 full waves, zero lane waste
#define NCH 8                // d-chunks of 128
#define DCH 128
#define CPB 4                // classes per scores block
#define NCQ (CC / CPB)       // 20 class-groups -> grid 2080 blocks
#define PG 16                // classes per pool block (4 per wave)
#define PT 8                 // pool d-tiles (128 each)
#define TWO_LOG2E 2.8853900817779268f

// ---------------- K1: scores (R3/R5-proven structure) + imgT side-product ----
// UNCHANGED from R7 (68 us, ~1.5x transcendental floor).
__global__ __launch_bounds__(256) void scores_k(const float* __restrict__ img,
                                                const float* __restrict__ word,
                                                const float* __restrict__ fa,
                                                float* __restrict__ partial,
                                                float* __restrict__ imgT) {
    const int g = blockIdx.x * 256 + threadIdx.x;
    if (g >= NSP) return;                           // wave-uniform exit
    const int b  = g / HW;
    const int hw = g - b * HW;
    const int d0 = blockIdx.y * DCH;
    const int c0 = blockIdx.z * CPB;

    const float* ip = img + ((size_t)b * DD + d0) * HW + hw;

    float p[CPB];
#pragma unroll
    for (int k = 0; k < CPB; ++k) p[k] = 0.f;

    for (int q = 0; q < DCH / 32; ++q) {            // 4 quarters of 32 d
        float iv[32];
        const float* qp = ip + (size_t)q * 32 * HW;
#pragma unroll
        for (int i = 0; i < 32; ++i)
            iv[i] = qp[(size_t)i * HW];

        if (blockIdx.z == 0) {                       // block-uniform branch
            float4* tp = (float4*)(imgT + (size_t)g * DD + d0 + q * 32);
#pragma unroll
            for (int i = 0; i < 8; ++i)
                tp[i] = make_float4(iv[4 * i], iv[4 * i + 1], iv[4 * i + 2], iv[4 * i + 3]);
        }

#pragma unroll
        for (int i = 0; i < 32; ++i)
            iv[i] *= TWO_LOG2E;                      // exp2(iv*w) == e^{2x}

        const float* fp = fa + d0 + q * 32;          // uniform -> SGPRs
#pragma unroll
        for (int k = 0; k < CPB; ++k) {
            const float* wp = word + (size_t)(c0 + k) * DD + d0 + q * 32;
            float p0 = 0.f, p1 = 0.f;
#pragma unroll
            for (int i = 0; i < 32; i += 2) {
                float y0 = iv[i]     * wp[i];
                float y1 = iv[i + 1] * wp[i + 1];
                float e0 = __builtin_amdgcn_exp2f(y0);
                float e1 = __builtin_amdgcn_exp2f(y1);
                float r0 = __builtin_amdgcn_rcpf(e0 + 1.f);
                float r1 = __builtin_amdgcn_rcpf(e1 + 1.f);
                p0 = fmaf(fp[i],     r0, p0);
                p1 = fmaf(fp[i + 1], r1, p1);
            }
            p[k] += p0 + p1;
        }
    }

#pragma unroll
    for (int k = 0; k < CPB; ++k)
        partial[(((size_t)b * NCH + blockIdx.y) * CC + (c0 + k)) * HW + hw]
            = (-TWO_LOG2E) * p[k];
}

// ---------------- K2: fused softmax + pooling, TRAFFIC-TILED ----------------
// Grid (16 b, 8 d-tiles of 128, 5 c-groups of 16) = 640 blocks x 4 waves
// = 10 waves/CU. imgT re-read only 80/16 = 5x (64 MB, was 256 MB in R7) --
// the L3 data-volume roofline was R7's real limiter.
// Phase S: wave w computes softmaxes for classes cg+4w..+3 from the 8-chunk
//   partials (coalesced loads, shuffle reduce, exp2) -> 12.5 KB LDS coef.
// Phase P: thread owns d-pair d0+2l (float2, coalesced 512 B/instr); per
//   h-quad: 4 float2 VMEM + 4 broadcast ds_read_b128 + 32 v_fma.
__global__ __launch_bounds__(256) void pool3_k(const float* __restrict__ imgT,
                                               const float* __restrict__ partial,
                                               float* __restrict__ out) {
    __shared__ float ct[PG * HW];                 // 12544 B
    const int b  = blockIdx.x;
    const int d0 = blockIdx.y * 128;
    const int cg = blockIdx.z * PG;
    const int t  = threadIdx.x;
    const int w  = t >> 6, l = t & 63;

    // ---- Phase S: 4 softmaxes per wave ----
#pragma unroll
    for (int rr = 0; rr < 4; ++rr) {
        const int r = 4 * w + rr;
        const int c = cg + r;
        float x0 = 0.f, x1 = 0.f, x2 = 0.f, x3 = 0.f;
#pragma unroll
        for (int ch = 0; ch < NCH; ++ch) {
            const float* pp = partial + (((size_t)b * NCH + ch) * CC + c) * HW;
            x0 += pp[l];
            x1 += pp[l + 64];
            x2 += pp[l + 128];
            if (l < HW - 192) x3 += pp[l + 192];
        }
        float x3m = (l < HW - 192) ? x3 : -3.4e38f;

        float m = fmaxf(fmaxf(x0, x1), fmaxf(x2, x3m));
#pragma unroll
        for (int off = 32; off >= 1; off >>= 1) m = fmaxf(m, __shfl_xor(m, off, 64));

        float e0 = __builtin_amdgcn_exp2f(x0 - m);
        float e1 = __builtin_amdgcn_exp2f(x1 - m);
        float e2 = __builtin_amdgcn_exp2f(x2 - m);
        float e3 = (l < HW - 192) ? __builtin_amdgcn_exp2f(x3 - m) : 0.f;

        float s = (e0 + e1) + (e2 + e3);
#pragma unroll
        for (int off = 32; off >= 1; off >>= 1) s += __shfl_xor(s, off, 64);

        float inv = __builtin_amdgcn_rcpf(s);
        float* cr = ct + r * HW;
        cr[l]       = e0 * inv;
        cr[l + 64]  = e1 * inv;
        cr[l + 128] = e2 * inv;
        if (l < HW - 192) cr[l + 192] = e3 * inv;
    }
    __syncthreads();

    // ---- Phase P: pooling; thread = d-pair, wave = 4 classes ----
    const float* ib = imgT + (size_t)b * HW * DD + d0 + 2 * l;
    const float* cr0 = ct + (4 * w) * HW;

    float2 a0 = {0, 0}, a1 = {0, 0}, a2 = {0, 0}, a3 = {0, 0};
    for (int h = 0; h < HW; h += 4) {
        float2 i0 = *(const float2*)(ib + (size_t)(h    ) * DD);
        float2 i1 = *(const float2*)(ib + (size_t)(h + 1) * DD);
        float2 i2 = *(const float2*)(ib + (size_t)(h + 2) * DD);
        float2 i3 = *(const float2*)(ib + (size_t)(h + 3) * DD);
        float4 c0v = *(const float4*)(cr0 + h);               // broadcast b128
        float4 c1v = *(const float4*)(cr0 + HW + h);
        float4 c2v = *(const float4*)(cr0 + 2 * HW + h);
        float4 c3v = *(const float4*)(cr0 + 3 * HW + h);
#define ACC2(A, CV)                                                              \
        A.x = fmaf(CV.x, i0.x, fmaf(CV.y, i1.x, fmaf(CV.z, i2.x, fmaf(CV.w, i3.x, A.x)))); \
        A.y = fmaf(CV.x, i0.y, fmaf(CV.y, i1.y, fmaf(CV.z, i2.y, fmaf(CV.w, i3.y, A.y))));
        ACC2(a0, c0v)
        ACC2(a1, c1v)
        ACC2(a2, c2v)
        ACC2(a3, c3v)
#undef ACC2
    }

    float* ob = out + ((size_t)b * CC + cg + 4 * w) * DD + d0 + 2 * l;
    *(float2*)(ob)                  = a0;
    *(float2*)(ob + DD)             = a1;
    *(float2*)(ob + 2 * (size_t)DD) = a2;
    *(float2*)(ob + 3 * (size_t)DD) = a3;
}

extern "C" void kernel_launch(void* const* d_in, const int* in_sizes, int n_in,
                              void* d_out, int out_size, void* d_ws, size_t ws_size,
                              hipStream_t stream) {
    // inputs: [0]=batch_size(int,1) [1]=img [2]=word [3]=fc_a_w [4]=fc_a_b
    const float* img  = (const float*)d_in[1];
    const float* word = (const float*)d_in[2];
    const float* fa   = (const float*)d_in[3];
    float* out = (float*)d_out;

    // workspace (floats): partial[16][8][80][196] = 8.03 MB | imgT[3136][1024] = 12.85 MB
    float* partial = (float*)d_ws;
    float* imgT    = partial + (size_t)BB * NCH * CC * HW;

    scores_k<<<dim3((NSP + 255) / 256, NCH, NCQ), 256, 0, stream>>>(img, word, fa, partial, imgT);
    pool3_k<<<dim3(BB, PT, CC / PG), 256, 0, stream>>>(imgT, partial, out);
}